// Round 1
// baseline (11.769 us; speedup 1.0000x reference)
//
#include <hip/hip_runtime.h>

// Closed-form reduction of the 1000-iter soft-threshold loop:
//   a <= 0.5 -> scores=0, x decays below 0.5 -> output exactly 0
//   a  > 0.5 -> x grows by >=0.00498/step, clamps to exactly 1.0 -> output 1
// So: out[i] = (in[i] > 0.5f) ? 1.0f : 0.0f  (bit-exact vs fp32 reference)

__global__ void sp_post_threshold_kernel(const float4* __restrict__ in,
                                         float4* __restrict__ out,
                                         int n4) {
    int i = blockIdx.x * blockDim.x + threadIdx.x;
    int stride = gridDim.x * blockDim.x;
    for (; i < n4; i += stride) {
        float4 v = in[i];
        float4 r;
        r.x = (v.x > 0.5f) ? 1.0f : 0.0f;
        r.y = (v.y > 0.5f) ? 1.0f : 0.0f;
        r.z = (v.z > 0.5f) ? 1.0f : 0.0f;
        r.w = (v.w > 0.5f) ? 1.0f : 0.0f;
        out[i] = r;
    }
}

// Tail handler for element counts not divisible by 4 (not expected here,
// but keeps the kernel correct for any size).
__global__ void sp_post_threshold_tail(const float* __restrict__ in,
                                       float* __restrict__ out,
                                       int start, int n) {
    int i = start + blockIdx.x * blockDim.x + threadIdx.x;
    if (i < n) {
        float v = in[i];
        out[i] = (v > 0.5f) ? 1.0f : 0.0f;
    }
}

extern "C" void kernel_launch(void* const* d_in, const int* in_sizes, int n_in,
                              void* d_out, int out_size, void* d_ws, size_t ws_size,
                              hipStream_t stream) {
    const float* in = (const float*)d_in[0];
    float* out = (float*)d_out;
    int n = in_sizes[0];          // 2*1024*1024 = 2,097,152 (== out_size)

    int n4 = n / 4;
    const int block = 256;
    int grid = (n4 + block - 1) / block;
    if (grid > 8192) grid = 8192;   // grid-stride beyond this (not hit at this size)
    if (grid > 0) {
        sp_post_threshold_kernel<<<grid, block, 0, stream>>>(
            (const float4*)in, (float4*)out, n4);
    }

    int tail_start = n4 * 4;
    int tail = n - tail_start;
    if (tail > 0) {
        sp_post_threshold_tail<<<1, 64, 0, stream>>>(in, out, tail_start, n);
    }
}

// Round 2
// 10.694 us; speedup vs baseline: 1.1005x; 1.1005x over previous
//
#include <hip/hip_runtime.h>

// Closed-form reduction of the 1000-iter soft-threshold loop (verified
// bit-exact in round 1, absmax = 0):
//   a <= 0.5 -> scores=0, x decays below 0.5 -> output exactly 0
//   a  > 0.5 -> x grows >=0.00498/step, clamps to exactly 1.0 -> output 1
// So: out[i] = (in[i] > 0.5f) ? 1.0f : 0.0f
//
// Purely memory-bound: 8 MiB read + 8 MiB write. Measured ~11.8 us is
// dominated by launch overhead (data-movement floor ~2.5 us at 6.85 TB/s).

__global__ __launch_bounds__(256) void sp_post_threshold_kernel(
        const float4* __restrict__ in,
        float4* __restrict__ out) {
    // Each thread handles 2 contiguous float4s (32 B). Grid sized exactly.
    int i = (blockIdx.x * 256 + threadIdx.x) * 2;
    float4 a = in[i];
    float4 b = in[i + 1];
    float4 ra, rb;
    ra.x = (a.x > 0.5f) ? 1.0f : 0.0f;
    ra.y = (a.y > 0.5f) ? 1.0f : 0.0f;
    ra.z = (a.z > 0.5f) ? 1.0f : 0.0f;
    ra.w = (a.w > 0.5f) ? 1.0f : 0.0f;
    rb.x = (b.x > 0.5f) ? 1.0f : 0.0f;
    rb.y = (b.y > 0.5f) ? 1.0f : 0.0f;
    rb.z = (b.z > 0.5f) ? 1.0f : 0.0f;
    rb.w = (b.w > 0.5f) ? 1.0f : 0.0f;
    out[i] = ra;
    out[i + 1] = rb;
}

// Generic fallback for sizes not divisible by 2048 floats (not hit at
// the benchmark size of 2^21, but keeps kernel_launch correct generally).
__global__ void sp_post_threshold_generic(const float* __restrict__ in,
                                          float* __restrict__ out,
                                          int start, int n) {
    int i = start + blockIdx.x * blockDim.x + threadIdx.x;
    int stride = gridDim.x * blockDim.x;
    for (; i < n; i += stride) {
        out[i] = (in[i] > 0.5f) ? 1.0f : 0.0f;
    }
}

extern "C" void kernel_launch(void* const* d_in, const int* in_sizes, int n_in,
                              void* d_out, int out_size, void* d_ws, size_t ws_size,
                              hipStream_t stream) {
    const float* in = (const float*)d_in[0];
    float* out = (float*)d_out;
    int n = in_sizes[0];   // 2,097,152 at bench size

    // Fast path: n divisible by 256 threads * 8 floats = 2048.
    int chunk = 256 * 8;
    int main_n = (n / chunk) * chunk;
    int grid = main_n / chunk;          // 1024 blocks at bench size
    if (grid > 0) {
        sp_post_threshold_kernel<<<grid, 256, 0, stream>>>(
            (const float4*)in, (float4*)out);
    }
    if (main_n < n) {
        int rem = n - main_n;
        int b = (rem + 255) / 256;
        if (b > 256) b = 256;
        sp_post_threshold_generic<<<b, 256, 0, stream>>>(in, out, main_n, n);
    }
}